// Round 13
// baseline (1621.578 us; speedup 1.0000x reference)
//
#include <hip/hip_runtime.h>
#include <cstddef>

#define NN 50000
#define NP 50048      // padded rows (391 * 128)
#define RT 391        // row tiles

typedef unsigned short u16;
typedef __attribute__((ext_vector_type(8))) short bf16x8;
typedef __attribute__((ext_vector_type(4))) float f32x4;

__device__ __forceinline__ float bf2f(u16 h){
  union { unsigned u; float f; } x; x.u = ((unsigned)h) << 16; return x.f;
}
__device__ __forceinline__ u16 f2bf(float f){
  union { float f; unsigned u; } x; x.f = f;
  unsigned r = x.u + 0x7fffu + ((x.u >> 16) & 1u);
  return (u16)(r >> 16);
}
__device__ __forceinline__ float silu_f(float v){
  return v / (1.f + __expf(-v));
}
__device__ __forceinline__ void gll16(const u16* g, u16* l){
  __builtin_amdgcn_global_load_lds(
      (const __attribute__((address_space(1))) unsigned int*)g,
      (__attribute__((address_space(3))) unsigned int*)l, 16, 0, 0);
}
// bijective XCD-chunked block-id swizzle (m204)
__device__ __forceinline__ int xcd_swz(int hw, int nblk){
  int q = nblk >> 3, r = nblk & 7;
  int xcd = hw & 7, j = hw >> 3;
  return (xcd < r ? xcd*(q+1) : r*(q+1) + (xcd - r)*q) + j;
}
#define SWZ(row) (((row) >> 1) & 3)

// ---------------- weight convert + transpose to bf16 (tiled, coalesced) ----
__global__ __launch_bounds__(256)
void k_wt(const float* b0,const float* b1,const float* b2,const float* b3,
          const float* b4,const float* b5,
          const float* s0,const float* s1,const float* s2,const float* s3,
          const float* s4,const float* s5, u16* __restrict__ dst){
  __shared__ float t[64][68];
  const int m = blockIdx.y;
  const bool big = (m < 6);
  const int K = big ? 512 : 256, C = big ? 512 : 128;
  const int tC = C >> 6;
  const int tiles = (K >> 6) * tC;
  if((int)blockIdx.x >= tiles) return;
  const int k0 = ((int)blockIdx.x / tC) << 6, c0 = ((int)blockIdx.x % tC) << 6;
  const float* src = m==0?b0:m==1?b1:m==2?b2:m==3?b3:m==4?b4:m==5?b5:
                     m==6?s0:m==7?s1:m==8?s2:m==9?s3:m==10?s4:s5;
  u16* d = dst + (big ? (size_t)m*262144 : (size_t)(6*262144) + (size_t)(m-6)*32768);
  const int tr = threadIdx.x >> 2, tc = (threadIdx.x & 3) << 4;
  const float* sp = src + (size_t)(k0 + tr)*C + c0 + tc;
#pragma unroll
  for(int j=0;j<16;j+=4) *(f32x4*)&t[tr][tc + j] = *(const f32x4*)(sp + j);
  __syncthreads();
  u16* dp = d + (size_t)(c0 + tr)*K + k0 + tc;
#pragma unroll
  for(int j=0;j<16;j++) dp[j] = f2bf(t[tc + j][tr]);
}

// -------- prep: A0 = bf16[ s | ||v|| ] [NP,512]; XVp = bf16 planes [NP,3,256]
__global__ __launch_bounds__(256)
void k_prep(const float* __restrict__ x, u16* __restrict__ A0,
            u16* __restrict__ XVp){
  const int n = blockIdx.x;
  const int t = threadIdx.x;
  u16* row = A0 + (size_t)n * 512;
  u16* xv  = XVp + (size_t)n * 768;
  if(n >= NN){
    row[t] = 0; row[256 + t] = 0;
    xv[t] = 0; xv[256 + t] = 0; xv[512 + t] = 0;
    return;
  }
  const float* xr = x + (size_t)n * 1024;
  row[t] = f2bf(xr[t]);
  float a = xr[256 + 3*t], b = xr[256 + 3*t + 1], c = xr[256 + 3*t + 2];
  row[256 + t] = f2bf(sqrtf(a*a + b*b + c*c));
  xv[t] = f2bf(a); xv[256 + t] = f2bf(b); xv[512 + t] = f2bf(c);
}

// ------- 128x128 MFMA core: A+B LDS ring-2 (32 KB), vmcnt(0), 1 barrier/step
// Stage kt+1 issued one full loop body before use; latency hidden by
// 5-block/CU TLP.
template<int K>
__device__ __forceinline__ void gemm_core(const u16* __restrict__ A, int lda,
                                          const u16* __restrict__ Bt, int ldb,
                                          u16* lds, f32x4 acc[4][4]){
  constexpr int NT = K / 32;
  static_assert(NT >= 2, "");
  const int tid  = threadIdx.x;
  const int lane = tid & 63;
  const int wid  = tid >> 6;
  const int wm = (wid >> 1) << 6;
  const int wn = (wid & 1) << 6;
  const int lr = lane & 15;
  const int lh = lane >> 4;
#pragma unroll
  for(int mi=0;mi<4;mi++)
#pragma unroll
    for(int ni=0;ni<4;ni++) acc[mi][ni] = (f32x4)(0.f);

  const int r0 = tid >> 2, s0 = tid & 3, r1 = (tid + 256) >> 2;
  const u16* agA0 = A  + (size_t)r0*lda + (size_t)((s0 ^ SWZ(r0)) * 8);
  const u16* agA1 = A  + (size_t)r1*lda + (size_t)((s0 ^ SWZ(r1)) * 8);
  const u16* agB0 = Bt + (size_t)r0*ldb + (size_t)((s0 ^ SWZ(r0)) * 8);
  const u16* agB1 = Bt + (size_t)r1*ldb + (size_t)((s0 ^ SWZ(r1)) * 8);

#define STAGE(b, k0)                                         \
  { u16* lbase = lds + (size_t)(b) * 8192;                   \
    gll16(agA0 + (k0), lbase + tid*8);                       \
    gll16(agA1 + (k0), lbase + (tid+256)*8);                 \
    gll16(agB0 + (k0), lbase + 4096 + tid*8);                \
    gll16(agB1 + (k0), lbase + 4096 + (tid+256)*8); }

  STAGE(0, 0)
  for(int kt = 0; kt < NT; ++kt){
    const int cur = kt & 1;
    asm volatile("s_waitcnt vmcnt(0)" ::: "memory");   // slot kt landed
    __builtin_amdgcn_s_barrier();
    {
      int kf = kt + 1; if(kf > NT-1) kf = NT-1;        // clamp: L2-hot tail
      STAGE(cur ^ 1, kf*32)                            // buffer consumed at kt-1
    }
    const u16* la = lds + (size_t)cur * 8192;
    const u16* lb = la + 4096;
    bf16x8 af[4], bv[4];
#pragma unroll
    for(int i=0;i<4;i++){
      const int ra = wm + i*16 + lr;
      af[i] = *(const bf16x8*)(la + ra*32 + ((lh ^ SWZ(ra)) * 8));
      const int rb = wn + i*16 + lr;
      bv[i] = *(const bf16x8*)(lb + rb*32 + ((lh ^ SWZ(rb)) * 8));
    }
    __builtin_amdgcn_s_setprio(1);
#pragma unroll
    for(int mi=0;mi<4;mi++)
#pragma unroll
      for(int ni=0;ni<4;ni++)
        acc[mi][ni] = __builtin_amdgcn_mfma_f32_16x16x32_bf16(
                          af[mi], bv[ni], acc[mi][ni], 0, 0, 0);
    __builtin_amdgcn_s_setprio(0);
  }
#undef STAGE
  asm volatile("s_waitcnt vmcnt(0)" ::: "memory");  // drain before LDS reuse
  __builtin_amdgcn_s_barrier();
}

// C-tile LDS staging (bf16, XOR-swizzled: byte ^= (row&7)<<4)
__device__ __forceinline__ void cstage_write(u16* lds, int rl, int cl, float v){
  const int b = ((rl << 8) + (cl << 1)) ^ ((rl & 7) << 4);
  *(u16*)((char*)lds + b) = f2bf(v);
}
__device__ __forceinline__ bf16x8 cstage_read(const u16* lds, int rl, int cl){
  const int b = ((rl << 8) + (cl << 1)) ^ ((rl & 7) << 4);
  return *(const bf16x8*)((const char*)lds + b);
}

// ---------------- fc GEMMs: [NP,512]@[512,512], ring-2, 5 blocks/CU ---------
// EPI 0: silu(acc+bias) -> bf16 [n*512+c]
// EPI 1: c<256 silu -> [n*1024+c]; c>=256 raw g, out = xv_plane * g (bf16)
// EPI 2: same but vs TPV planes
template<int EPI, int NZ>
__global__ __launch_bounds__(256, 5)
void k_fc(const u16* __restrict__ Al, const u16* __restrict__ Ar,
          const u16* __restrict__ Btl, const u16* __restrict__ Btr,
          const float* __restrict__ bl, const float* __restrict__ br_,
          u16* __restrict__ ol, u16* __restrict__ orr,
          const u16* __restrict__ gsrc){
  __shared__ u16 lds[16384];     // 32 KB: ring-2 x 16 KB; C-stage reuses all
  const int nblk = RT * 4 * NZ;
  const int L = xcd_swz(blockIdx.x, nblk);
  int rowTileI, colTileI, z;
  if(NZ == 2){ rowTileI = L >> 3; int sub = L & 7; colTileI = sub >> 1; z = sub & 1; }
  else       { rowTileI = L >> 2; colTileI = L & 3; z = 0; }
  const u16* A  = z ? Ar  : Al;
  const u16* Bt = z ? Btr : Btl;
  const float* bias = z ? br_ : bl;
  u16* o = z ? orr : ol;
  const int tileRow = rowTileI << 7;
  const int colTile = colTileI << 7;
  f32x4 acc[4][4];
  gemm_core<512>(A + (size_t)tileRow*512, 512, Bt + (size_t)colTile*512, 512,
                 lds, acc);
  const int tid = threadIdx.x, lane = tid & 63, wid = tid >> 6;
  const int wm=(wid>>1)<<6, wn=(wid&1)<<6, lr=lane&15, lh=lane>>4;
  const bool gateTile = (EPI != 0) && (colTile >= 256);
#pragma unroll
  for(int mi=0;mi<4;mi++){
#pragma unroll
    for(int ni=0;ni<4;ni++){
      const int cl = wn + ni*16 + lr;
      const float bv = bias[colTile + cl];
#pragma unroll
      for(int r=0;r<4;r++){
        const int rl = wm + mi*16 + lh*4 + r;
        float v = acc[mi][ni][r] + bv;
        if(!gateTile) v = silu_f(v);
        cstage_write(lds, rl, cl, v);
      }
    }
  }
  __syncthreads();
  // lane-coalesced write-out: consecutive lanes -> consecutive 16B chunks
  if(!gateTile){
    const int ldo = (EPI == 0) ? 512 : 1024;
#pragma unroll
    for(int j=0;j<8;j++){
      const int q = j*256 + tid;            // 2048 chunks = 128 rows x 16
      const int row = q >> 4, slot = q & 15;
      bf16x8 v = cstage_read(lds, row, slot*8);
      *(bf16x8*)(o + (size_t)(tileRow + row)*ldo + colTile + slot*8) = v;
    }
  } else {
    const int ub = colTile - 256;           // 0 or 128
#pragma unroll 4
    for(int j=0;j<24;j++){
      const int q = j*256 + tid;            // 6144 chunks = 128 rows x 3pl x 16
      const int row = q / 48, w = q - row*48;
      const int pl = w >> 4, slot = w & 15;
      const int n = tileRow + row;
      bf16x8 g8 = cstage_read(lds, row, slot*8);
      bf16x8 x8 = *(const bf16x8*)(gsrc + (size_t)n*768 + pl*256 + ub + slot*8);
      bf16x8 o8;
#pragma unroll
      for(int e=0;e<8;e++)
        o8[e] = (short)f2bf(bf2f((u16)x8[e]) * bf2f((u16)g8[e]));
      *(bf16x8*)(o + (size_t)n*1024 + 256 + pl*256 + ub + slot*8) = o8;
    }
  }
}

// ---------------- o3 GEMMs: [NP,256]@[256,128], ring-2, 5 blocks/CU ---------
// EPI 0: branch o3 -> bf16 [n*512 + comp*128 + c]
// EPI 1: final: comp0 -> fp32 out scalars; comp1..3 -> fp32 planes PVp[N,3,128]
template<int EPI>
__global__ __launch_bounds__(256, 5)
void k_o3(const u16* __restrict__ AL, const u16* __restrict__ AR,
          const u16* __restrict__ W0L, const u16* __restrict__ W1L,
          const u16* __restrict__ W0R, const u16* __restrict__ W1R,
          const float* __restrict__ bL, const float* __restrict__ bR,
          u16* __restrict__ oL, u16* __restrict__ oR,
          float* __restrict__ fout, float* __restrict__ PVp){
  __shared__ u16 lds[16384];
  const int nblk = RT * ((EPI==0) ? 8 : 4);
  const int L = xcd_swz(blockIdx.x, nblk);
  int rowTileI, br, comp;
  if(EPI == 0){ rowTileI = L >> 3; int sub = L & 7; br = sub >> 2; comp = sub & 3; }
  else        { rowTileI = L >> 2; comp = L & 3; br = 0; }
  const u16* A  = br ? AR : AL;
  const u16* Bt = br ? (comp ? W1R : W0R) : (comp ? W1L : W0L);
  const float* bias = br ? bR : bL;
  u16* o16 = br ? oR : oL;
  const int aoff = comp ? (256 + (comp-1)*256) : 0;
  const int tileRow = rowTileI << 7;
  f32x4 acc[4][4];
  gemm_core<256>(A + (size_t)tileRow*1024 + aoff, 1024, Bt, 256, lds, acc);
  const int tid = threadIdx.x, lane = tid & 63, wid = tid >> 6;
  const int wm=(wid>>1)<<6, wn=(wid&1)<<6, lr=lane&15, lh=lane>>4;
  if(EPI == 0){
#pragma unroll
    for(int mi=0;mi<4;mi++){
#pragma unroll
      for(int ni=0;ni<4;ni++){
        const int cl = wn + ni*16 + lr;
#pragma unroll
        for(int r=0;r<4;r++){
          const int rl = wm + mi*16 + lh*4 + r;
          float v = acc[mi][ni][r] * 0.0625f;
          if(comp == 0) v += bias[cl];
          cstage_write(lds, rl, cl, v);
        }
      }
    }
    __syncthreads();
#pragma unroll
    for(int j=0;j<8;j++){
      const int q = j*256 + tid;
      const int row = q >> 4, slot = q & 15;
      bf16x8 v = cstage_read(lds, row, slot*8);
      *(bf16x8*)(o16 + (size_t)(tileRow + row)*512 + comp*128 + slot*8) = v;
    }
  } else {
    // fp32 LDS staging in four [32][128] passes; XOR-swizzled (16B granules)
    float* lf = (float*)lds;
#pragma unroll
    for(int qu=0; qu<4; ++qu){
      const int mi0 = (qu & 1) * 2;
      if((wm >> 6) == (qu >> 1)){
#pragma unroll
        for(int mi=mi0; mi<mi0+2; mi++){
#pragma unroll
          for(int ni=0;ni<4;ni++){
            const int cl = wn + ni*16 + lr;
#pragma unroll
            for(int r=0;r<4;r++){
              const int rl = (mi - mi0)*16 + lh*4 + r;   // 0..31
              float v = acc[mi][ni][r] * 0.0625f;
              if(comp == 0) v += bias[cl];
              const int b = (rl*512 + cl*4) ^ ((rl & 7) << 4);
              *(float*)((char*)lf + b) = v;
            }
          }
        }
      }
      __syncthreads();
#pragma unroll
      for(int j=0;j<4;j++){
        const int q = j*256 + tid;          // 1024 chunks = 32 rows x 32
        const int row = q >> 5, slot = q & 31;
        const int n = tileRow + qu*32 + row;
        const int b = (row*512 + slot*16) ^ ((row & 7) << 4);
        f32x4 v = *(const f32x4*)((const char*)lf + b);
        if(n < NN){
          if(comp == 0) *(f32x4*)(fout + (size_t)n*512 + slot*4) = v;
          else *(f32x4*)(PVp + (size_t)n*384 + (size_t)(comp-1)*128 + slot*4) = v;
        }
      }
      __syncthreads();
    }
  }
}

// ---------------- final interleave: PVp fp32 planes -> out[n,128+3c+p] -----
__global__ __launch_bounds__(256)
void k_out(const float* __restrict__ PVp, float* __restrict__ out){
  const int n = (blockIdx.x << 1) + (threadIdx.x >> 7);
  if(n >= NN) return;
  const int c = threadIdx.x & 127;
  const float* s = PVp + (size_t)n*384 + c;
  const float v0 = s[0], v1 = s[128], v2 = s[256];
  float* d = out + (size_t)n*512 + 128 + c*3;
  d[0] = v0; d[1] = v1; d[2] = v2;
}

// ------------- TP + residual + norms: builds A2 [NP,512], TPV [NP,3,256] ---
// residual read from A2's old contents (= A0 s-half) and XVp bf16 planes
__global__ __launch_bounds__(256)
void k_tp(const u16* __restrict__ OL, const u16* __restrict__ ORr,
          const u16* __restrict__ XVpp,
          const float* __restrict__ w_ss, const float* __restrict__ w_sv,
          const float* __restrict__ w_vs, const float* __restrict__ w_vv,
          u16* A2, u16* __restrict__ TPV){
  const int n = (blockIdx.x << 1) + (threadIdx.x >> 7);
  const int h = threadIdx.x & 127;
  const u16* ol  = OL  + (size_t)n * 512;
  const u16* orv = ORr + (size_t)n * 512;
  const float ls = bf2f(ol[h]),  rs = bf2f(orv[h]);
  const float lv0=bf2f(ol[128+h]),  lv1=bf2f(ol[256+h]),  lv2=bf2f(ol[384+h]);
  const float rv0=bf2f(orv[128+h]), rv1=bf2f(orv[256+h]), rv2=bf2f(orv[384+h]);
  const float wss=w_ss[h], wsv=w_sv[h], wvs=w_vs[h], wvv=w_vv[h];
  float sa = wss * ls * rs;
  float sb = wvv * (lv0*rv0 + lv1*rv1 + lv2*rv2) * 0.5773502691896258f;
  float va0 = wsv*ls*rv0, va1 = wsv*ls*rv1, va2 = wsv*ls*rv2;
  float vb0 = wvs*lv0*rs, vb1 = wvs*lv1*rs, vb2 = wvs*lv2*rs;
  if(n < NN){
    const u16* a0 = A2 + (size_t)n * 512;
    const u16* xv = XVpp + (size_t)n * 768;
    sa += bf2f(a0[h]); sb += bf2f(a0[128 + h]);
    va0 += bf2f(xv[h]);       va1 += bf2f(xv[256 + h]);  va2 += bf2f(xv[512 + h]);
    vb0 += bf2f(xv[128 + h]); vb1 += bf2f(xv[384 + h]);  vb2 += bf2f(xv[640 + h]);
  }
  u16* a2 = A2 + (size_t)n * 512;
  a2[h]       = f2bf(sa);
  a2[128 + h] = f2bf(sb);
  a2[256 + h] = f2bf(sqrtf(va0*va0 + va1*va1 + va2*va2));
  a2[384 + h] = f2bf(sqrtf(vb0*vb0 + vb1*vb1 + vb2*vb2));
  u16* tv = TPV + (size_t)n * 768;
  tv[h]       = f2bf(va0);  tv[128 + h] = f2bf(vb0);
  tv[256 + h] = f2bf(va1);  tv[384 + h] = f2bf(vb1);
  tv[512 + h] = f2bf(va2);  tv[640 + h] = f2bf(vb2);
}

extern "C" void kernel_launch(void* const* d_in, const int* in_sizes, int n_in,
                              void* d_out, int out_size, void* d_ws, size_t ws_size,
                              hipStream_t stream){
  const float* x      = (const float*)d_in[0];
  const float* fcl1_w = (const float*)d_in[1];  const float* fcl1_b = (const float*)d_in[2];
  const float* fcl2_w = (const float*)d_in[3];  const float* fcl2_b = (const float*)d_in[4];
  const float* fcr1_w = (const float*)d_in[5];  const float* fcr1_b = (const float*)d_in[6];
  const float* fcr2_w = (const float*)d_in[7];  const float* fcr2_b = (const float*)d_in[8];
  const float* fcp1_w = (const float*)d_in[9];  const float* fcp1_b = (const float*)d_in[10];
  const float* fcp2_w = (const float*)d_in[11]; const float* fcp2_b = (const float*)d_in[12];
  const float* Wl0 = (const float*)d_in[13]; const float* bl0 = (const float*)d_in[14];
  const float* Wl1 = (const float*)d_in[15];
  const float* Wr0 = (const float*)d_in[16]; const float* br0 = (const float*)d_in[17];
  const float* Wr1 = (const float*)d_in[18];
  const float* Wp0 = (const float*)d_in[19]; const float* bp0 = (const float*)d_in[20];
  const float* Wp1 = (const float*)d_in[21];
  const float* w_ss = (const float*)d_in[22]; const float* w_sv = (const float*)d_in[23];
  const float* w_vs = (const float*)d_in[24]; const float* w_vv = (const float*)d_in[25];
  float* out = (float*)d_out;

  // ---- ws layout ----
  u16* WT = (u16*)d_ws;
  u16* wt_fcl1 = WT + 0*262144;
  u16* wt_fcl2 = WT + 1*262144;
  u16* wt_fcr1 = WT + 2*262144;
  u16* wt_fcr2 = WT + 3*262144;
  u16* wt_fcp1 = WT + 4*262144;
  u16* wt_fcp2 = WT + 5*262144;
  u16* wt_sm  = WT + 6*262144;
  u16* wt_Wl0 = wt_sm + 0*32768;
  u16* wt_Wl1 = wt_sm + 1*32768;
  u16* wt_Wr0 = wt_sm + 2*32768;
  u16* wt_Wr1 = wt_sm + 3*32768;
  u16* wt_Wp0 = wt_sm + 4*32768;
  u16* wt_Wp1 = wt_sm + 5*32768;
  char* base = (char*)d_ws;
  const size_t SZ512  = (size_t)NP * 512 * 2;
  const size_t SZ1024 = (size_t)NP * 1024 * 2;
  const size_t W_RES  = (size_t)4 << 20;
  u16* A0 = (u16*)(base + W_RES);                       // A0, later A2
  u16* Hl = (u16*)(base + W_RES + 1*SZ512);             // H_l, OL, H_p
  u16* Hr = (u16*)(base + W_RES + 2*SZ512);             // H_r, OR
  u16* BL = (u16*)(base + W_RES + 3*SZ512);             // ls/lv left; later TPV; later PVp
  u16* BR = (u16*)(base + W_RES + 3*SZ512 + SZ1024);    // ls/lv right; later PS/PV
  u16* XVp = (u16*)d_out;          // scratch: x vec bf16 planes [NP,3,256]
  float* PVp = (float*)BL;         // fp32 vec planes [NP,3,128]
  (void)ws_size; (void)in_sizes; (void)n_in; (void)out_size;

  // 1. weights -> bf16 transposed (tiled)
  k_wt<<<dim3(64,12), 256, 0, stream>>>(fcl1_w, fcl2_w, fcr1_w, fcr2_w, fcp1_w, fcp2_w,
                                        Wl0, Wl1, Wr0, Wr1, Wp0, Wp1, WT);
  // 2. A0 = [s | ||v||] bf16; XVp planes
  k_prep<<<NP, 256, 0, stream>>>(x, A0, XVp);
  // 3. fc1 (L,R)
  k_fc<0,2><<<RT*8, 256, 0, stream>>>(A0, A0, wt_fcl1, wt_fcr1,
                                      fcl1_b, fcr1_b, Hl, Hr, nullptr);
  // 4. fc2 (L,R) + gate vs XVp
  k_fc<1,2><<<RT*8, 256, 0, stream>>>(Hl, Hr, wt_fcl2, wt_fcr2,
                                      fcl2_b, fcr2_b, BL, BR, XVp);
  // 5. o3 linears (2 branches x 4 comps) -> OL(Hl), OR(Hr)
  k_o3<0><<<RT*8, 256, 0, stream>>>(BL, BR, wt_Wl0, wt_Wl1, wt_Wr0, wt_Wr1,
                                    bl0, br0, Hl, Hr, nullptr, nullptr);
  // 6. tensor product + residual + norms -> A2(A0), TPV(BL); residual from
  //    A0 s-half + XVp (bf16)
  k_tp<<<NP/2, 256, 0, stream>>>(Hl, Hr, XVp, w_ss, w_sv, w_vs, w_vv, A0, BL);
  // 7. fcp1
  k_fc<0,1><<<RT*4, 256, 0, stream>>>(A0, A0, wt_fcp1, wt_fcp1,
                                      fcp1_b, fcp1_b, Hl, Hl, nullptr);
  // 8. fcp2 + gate vs TPV(BL)
  k_fc<2,1><<<RT*4, 256, 0, stream>>>(Hl, Hl, wt_fcp2, wt_fcp2,
                                      fcp2_b, fcp2_b, BR, BR, BL);
  // 9. final o3 -> scalars to out; vectors to PVp (aliases BL, free now)
  k_o3<1><<<RT*4, 256, 0, stream>>>(BR, BR, wt_Wp0, wt_Wp1, nullptr, nullptr,
                                    bp0, bp0, nullptr, nullptr, out, PVp);
  // 10. interleave vector planes into out
  k_out<<<NN/2, 256, 0, stream>>>(PVp, out);
}

// Round 14
// 610.422 us; speedup vs baseline: 2.6565x; 2.6565x over previous
//
#include <hip/hip_runtime.h>
#include <cstddef>

#define NN 50000
#define NP 50048      // padded rows (391 * 128)
#define RT 391        // row tiles

typedef unsigned short u16;
typedef __attribute__((ext_vector_type(8))) short bf16x8;
typedef __attribute__((ext_vector_type(4))) float f32x4;

__device__ __forceinline__ float bf2f(u16 h){
  union { unsigned u; float f; } x; x.u = ((unsigned)h) << 16; return x.f;
}
__device__ __forceinline__ u16 f2bf(float f){
  union { float f; unsigned u; } x; x.f = f;
  unsigned r = x.u + 0x7fffu + ((x.u >> 16) & 1u);
  return (u16)(r >> 16);
}
__device__ __forceinline__ float silu_f(float v){
  return v / (1.f + __expf(-v));
}
__device__ __forceinline__ void gll16(const u16* g, u16* l){
  __builtin_amdgcn_global_load_lds(
      (const __attribute__((address_space(1))) unsigned int*)g,
      (__attribute__((address_space(3))) unsigned int*)l, 16, 0, 0);
}
// bijective XCD-chunked block-id swizzle (m204)
__device__ __forceinline__ int xcd_swz(int hw, int nblk){
  int q = nblk >> 3, r = nblk & 7;
  int xcd = hw & 7, j = hw >> 3;
  return (xcd < r ? xcd*(q+1) : r*(q+1) + (xcd - r)*q) + j;
}
#define SWZ(row) (((row) >> 1) & 3)

// ---------------- weight convert + transpose to bf16 (tiled, coalesced) ----
__global__ __launch_bounds__(256)
void k_wt(const float* b0,const float* b1,const float* b2,const float* b3,
          const float* b4,const float* b5,
          const float* s0,const float* s1,const float* s2,const float* s3,
          const float* s4,const float* s5, u16* __restrict__ dst){
  __shared__ float t[64][68];
  const int m = blockIdx.y;
  const bool big = (m < 6);
  const int K = big ? 512 : 256, C = big ? 512 : 128;
  const int tC = C >> 6;
  const int tiles = (K >> 6) * tC;
  if((int)blockIdx.x >= tiles) return;
  const int k0 = ((int)blockIdx.x / tC) << 6, c0 = ((int)blockIdx.x % tC) << 6;
  const float* src = m==0?b0:m==1?b1:m==2?b2:m==3?b3:m==4?b4:m==5?b5:
                     m==6?s0:m==7?s1:m==8?s2:m==9?s3:m==10?s4:s5;
  u16* d = dst + (big ? (size_t)m*262144 : (size_t)(6*262144) + (size_t)(m-6)*32768);
  const int tr = threadIdx.x >> 2, tc = (threadIdx.x & 3) << 4;
  const float* sp = src + (size_t)(k0 + tr)*C + c0 + tc;
#pragma unroll
  for(int j=0;j<16;j+=4) *(f32x4*)&t[tr][tc + j] = *(const f32x4*)(sp + j);
  __syncthreads();
  u16* dp = d + (size_t)(c0 + tr)*K + k0 + tc;
#pragma unroll
  for(int j=0;j<16;j++) dp[j] = f2bf(t[tc + j][tr]);
}

// -------- prep: A0 = bf16[ s | ||v|| ] [NP,512]; XVp = bf16 planes [NP,3,256]
__global__ __launch_bounds__(256)
void k_prep(const float* __restrict__ x, u16* __restrict__ A0,
            u16* __restrict__ XVp){
  const int n = blockIdx.x;
  const int t = threadIdx.x;
  u16* row = A0 + (size_t)n * 512;
  u16* xv  = XVp + (size_t)n * 768;
  if(n >= NN){
    row[t] = 0; row[256 + t] = 0;
    xv[t] = 0; xv[256 + t] = 0; xv[512 + t] = 0;
    return;
  }
  const float* xr = x + (size_t)n * 1024;
  row[t] = f2bf(xr[t]);
  float a = xr[256 + 3*t], b = xr[256 + 3*t + 1], c = xr[256 + 3*t + 2];
  row[256 + t] = f2bf(sqrtf(a*a + b*b + c*c));
  xv[t] = f2bf(a); xv[256 + t] = f2bf(b); xv[512 + t] = f2bf(c);
}

// ------- 128x128 MFMA core: A+B LDS ring-2 (32 KB), vmcnt(0), 1 barrier/step
// Stage kt+1 issued one full loop body before use; latency hidden by
// 4-block/CU TLP.
template<int K>
__device__ __forceinline__ void gemm_core(const u16* __restrict__ A, int lda,
                                          const u16* __restrict__ Bt, int ldb,
                                          u16* lds, f32x4 acc[4][4]){
  constexpr int NT = K / 32;
  static_assert(NT >= 2, "");
  const int tid  = threadIdx.x;
  const int lane = tid & 63;
  const int wid  = tid >> 6;
  const int wm = (wid >> 1) << 6;
  const int wn = (wid & 1) << 6;
  const int lr = lane & 15;
  const int lh = lane >> 4;
#pragma unroll
  for(int mi=0;mi<4;mi++)
#pragma unroll
    for(int ni=0;ni<4;ni++) acc[mi][ni] = (f32x4)(0.f);

  const int r0 = tid >> 2, s0 = tid & 3, r1 = (tid + 256) >> 2;
  const u16* agA0 = A  + (size_t)r0*lda + (size_t)((s0 ^ SWZ(r0)) * 8);
  const u16* agA1 = A  + (size_t)r1*lda + (size_t)((s0 ^ SWZ(r1)) * 8);
  const u16* agB0 = Bt + (size_t)r0*ldb + (size_t)((s0 ^ SWZ(r0)) * 8);
  const u16* agB1 = Bt + (size_t)r1*ldb + (size_t)((s0 ^ SWZ(r1)) * 8);

#define STAGE(b, k0)                                         \
  { u16* lbase = lds + (size_t)(b) * 8192;                   \
    gll16(agA0 + (k0), lbase + tid*8);                       \
    gll16(agA1 + (k0), lbase + (tid+256)*8);                 \
    gll16(agB0 + (k0), lbase + 4096 + tid*8);                \
    gll16(agB1 + (k0), lbase + 4096 + (tid+256)*8); }

  STAGE(0, 0)
  for(int kt = 0; kt < NT; ++kt){
    const int cur = kt & 1;
    asm volatile("s_waitcnt vmcnt(0)" ::: "memory");   // slot kt landed
    __builtin_amdgcn_s_barrier();
    {
      int kf = kt + 1; if(kf > NT-1) kf = NT-1;        // clamp: L2-hot tail
      STAGE(cur ^ 1, kf*32)                            // buffer consumed at kt-1
    }
    const u16* la = lds + (size_t)cur * 8192;
    const u16* lb = la + 4096;
    bf16x8 af[4], bv[4];
#pragma unroll
    for(int i=0;i<4;i++){
      const int ra = wm + i*16 + lr;
      af[i] = *(const bf16x8*)(la + ra*32 + ((lh ^ SWZ(ra)) * 8));
      const int rb = wn + i*16 + lr;
      bv[i] = *(const bf16x8*)(lb + rb*32 + ((lh ^ SWZ(rb)) * 8));
    }
    __builtin_amdgcn_s_setprio(1);
#pragma unroll
    for(int mi=0;mi<4;mi++)
#pragma unroll
      for(int ni=0;ni<4;ni++)
        acc[mi][ni] = __builtin_amdgcn_mfma_f32_16x16x32_bf16(
                          af[mi], bv[ni], acc[mi][ni], 0, 0, 0);
    __builtin_amdgcn_s_setprio(0);
  }
#undef STAGE
  asm volatile("s_waitcnt vmcnt(0)" ::: "memory");  // drain before LDS reuse
  __builtin_amdgcn_s_barrier();
}

// C-tile LDS staging (bf16, XOR-swizzled: byte ^= (row&7)<<4)
__device__ __forceinline__ void cstage_write(u16* lds, int rl, int cl, float v){
  const int b = ((rl << 8) + (cl << 1)) ^ ((rl & 7) << 4);
  *(u16*)((char*)lds + b) = f2bf(v);
}
__device__ __forceinline__ bf16x8 cstage_read(const u16* lds, int rl, int cl){
  const int b = ((rl << 8) + (cl << 1)) ^ ((rl & 7) << 4);
  return *(const bf16x8*)((const char*)lds + b);
}

// ---------------- fc GEMMs: [NP,512]@[512,512], ring-2, 4 blocks/CU ---------
// EPI 0: silu(acc+bias) -> bf16 [n*512+c]
// EPI 1: c<256 silu -> [n*1024+c]; c>=256 raw g, out = xv_plane * g (bf16)
// EPI 2: same but vs TPV planes
template<int EPI, int NZ>
__global__ __launch_bounds__(256, 4)
void k_fc(const u16* __restrict__ Al, const u16* __restrict__ Ar,
          const u16* __restrict__ Btl, const u16* __restrict__ Btr,
          const float* __restrict__ bl, const float* __restrict__ br_,
          u16* __restrict__ ol, u16* __restrict__ orr,
          const u16* __restrict__ gsrc){
  __shared__ u16 lds[16384];     // 32 KB: ring-2 x 16 KB; C-stage reuses all
  const int nblk = RT * 4 * NZ;
  const int L = xcd_swz(blockIdx.x, nblk);
  int rowTileI, colTileI, z;
  if(NZ == 2){ rowTileI = L >> 3; int sub = L & 7; colTileI = sub >> 1; z = sub & 1; }
  else       { rowTileI = L >> 2; colTileI = L & 3; z = 0; }
  const u16* A  = z ? Ar  : Al;
  const u16* Bt = z ? Btr : Btl;
  const float* bias = z ? br_ : bl;
  u16* o = z ? orr : ol;
  const int tileRow = rowTileI << 7;
  const int colTile = colTileI << 7;
  f32x4 acc[4][4];
  gemm_core<512>(A + (size_t)tileRow*512, 512, Bt + (size_t)colTile*512, 512,
                 lds, acc);
  const int tid = threadIdx.x, lane = tid & 63, wid = tid >> 6;
  const int wm=(wid>>1)<<6, wn=(wid&1)<<6, lr=lane&15, lh=lane>>4;
  const bool gateTile = (EPI != 0) && (colTile >= 256);
#pragma unroll
  for(int mi=0;mi<4;mi++){
#pragma unroll
    for(int ni=0;ni<4;ni++){
      const int cl = wn + ni*16 + lr;
      const float bv = bias[colTile + cl];
#pragma unroll
      for(int r=0;r<4;r++){
        const int rl = wm + mi*16 + lh*4 + r;
        float v = acc[mi][ni][r] + bv;
        if(!gateTile) v = silu_f(v);
        cstage_write(lds, rl, cl, v);
      }
    }
  }
  __syncthreads();
  // lane-coalesced write-out: consecutive lanes -> consecutive 16B chunks
  if(!gateTile){
    const int ldo = (EPI == 0) ? 512 : 1024;
#pragma unroll
    for(int j=0;j<8;j++){
      const int q = j*256 + tid;            // 2048 chunks = 128 rows x 16
      const int row = q >> 4, slot = q & 15;
      bf16x8 v = cstage_read(lds, row, slot*8);
      *(bf16x8*)(o + (size_t)(tileRow + row)*ldo + colTile + slot*8) = v;
    }
  } else {
    const int ub = colTile - 256;           // 0 or 128
#pragma unroll 4
    for(int j=0;j<24;j++){
      const int q = j*256 + tid;            // 6144 chunks = 128 rows x 3pl x 16
      const int row = q / 48, w = q - row*48;
      const int pl = w >> 4, slot = w & 15;
      const int n = tileRow + row;
      bf16x8 g8 = cstage_read(lds, row, slot*8);
      bf16x8 x8 = *(const bf16x8*)(gsrc + (size_t)n*768 + pl*256 + ub + slot*8);
      bf16x8 o8;
#pragma unroll
      for(int e=0;e<8;e++)
        o8[e] = (short)f2bf(bf2f((u16)x8[e]) * bf2f((u16)g8[e]));
      *(bf16x8*)(o + (size_t)n*1024 + 256 + pl*256 + ub + slot*8) = o8;
    }
  }
}

// ---------------- o3 GEMMs: [NP,256]@[256,128], ring-2, 4 blocks/CU ---------
// EPI 0: branch o3 -> bf16 [n*512 + comp*128 + c]
// EPI 1: final: comp0 -> fp32 out scalars; comp1..3 -> fp32 planes PVp[N,3,128]
template<int EPI>
__global__ __launch_bounds__(256, 4)
void k_o3(const u16* __restrict__ AL, const u16* __restrict__ AR,
          const u16* __restrict__ W0L, const u16* __restrict__ W1L,
          const u16* __restrict__ W0R, const u16* __restrict__ W1R,
          const float* __restrict__ bL, const float* __restrict__ bR,
          u16* __restrict__ oL, u16* __restrict__ oR,
          float* __restrict__ fout, float* __restrict__ PVp){
  __shared__ u16 lds[16384];
  const int nblk = RT * ((EPI==0) ? 8 : 4);
  const int L = xcd_swz(blockIdx.x, nblk);
  int rowTileI, br, comp;
  if(EPI == 0){ rowTileI = L >> 3; int sub = L & 7; br = sub >> 2; comp = sub & 3; }
  else        { rowTileI = L >> 2; comp = L & 3; br = 0; }
  const u16* A  = br ? AR : AL;
  const u16* Bt = br ? (comp ? W1R : W0R) : (comp ? W1L : W0L);
  const float* bias = br ? bR : bL;
  u16* o16 = br ? oR : oL;
  const int aoff = comp ? (256 + (comp-1)*256) : 0;
  const int tileRow = rowTileI << 7;
  f32x4 acc[4][4];
  gemm_core<256>(A + (size_t)tileRow*1024 + aoff, 1024, Bt, 256, lds, acc);
  const int tid = threadIdx.x, lane = tid & 63, wid = tid >> 6;
  const int wm=(wid>>1)<<6, wn=(wid&1)<<6, lr=lane&15, lh=lane>>4;
  if(EPI == 0){
#pragma unroll
    for(int mi=0;mi<4;mi++){
#pragma unroll
      for(int ni=0;ni<4;ni++){
        const int cl = wn + ni*16 + lr;
#pragma unroll
        for(int r=0;r<4;r++){
          const int rl = wm + mi*16 + lh*4 + r;
          float v = acc[mi][ni][r] * 0.0625f;
          if(comp == 0) v += bias[cl];
          cstage_write(lds, rl, cl, v);
        }
      }
    }
    __syncthreads();
#pragma unroll
    for(int j=0;j<8;j++){
      const int q = j*256 + tid;
      const int row = q >> 4, slot = q & 15;
      bf16x8 v = cstage_read(lds, row, slot*8);
      *(bf16x8*)(o16 + (size_t)(tileRow + row)*512 + comp*128 + slot*8) = v;
    }
  } else {
    // fp32 LDS staging in four [32][128] passes; XOR-swizzled (16B granules)
    float* lf = (float*)lds;
#pragma unroll
    for(int qu=0; qu<4; ++qu){
      const int mi0 = (qu & 1) * 2;
      if((wm >> 6) == (qu >> 1)){
#pragma unroll
        for(int mi=mi0; mi<mi0+2; mi++){
#pragma unroll
          for(int ni=0;ni<4;ni++){
            const int cl = wn + ni*16 + lr;
#pragma unroll
            for(int r=0;r<4;r++){
              const int rl = (mi - mi0)*16 + lh*4 + r;   // 0..31
              float v = acc[mi][ni][r] * 0.0625f;
              if(comp == 0) v += bias[cl];
              const int b = (rl*512 + cl*4) ^ ((rl & 7) << 4);
              *(float*)((char*)lf + b) = v;
            }
          }
        }
      }
      __syncthreads();
#pragma unroll
      for(int j=0;j<4;j++){
        const int q = j*256 + tid;          // 1024 chunks = 32 rows x 32
        const int row = q >> 5, slot = q & 31;
        const int n = tileRow + qu*32 + row;
        const int b = (row*512 + slot*16) ^ ((row & 7) << 4);
        f32x4 v = *(const f32x4*)((const char*)lf + b);
        if(n < NN){
          if(comp == 0) *(f32x4*)(fout + (size_t)n*512 + slot*4) = v;
          else *(f32x4*)(PVp + (size_t)n*384 + (size_t)(comp-1)*128 + slot*4) = v;
        }
      }
      __syncthreads();
    }
  }
}

// ---------------- final interleave: PVp fp32 planes -> out[n,128+3c+p] -----
__global__ __launch_bounds__(256)
void k_out(const float* __restrict__ PVp, float* __restrict__ out){
  const int n = (blockIdx.x << 1) + (threadIdx.x >> 7);
  if(n >= NN) return;
  const int c = threadIdx.x & 127;
  const float* s = PVp + (size_t)n*384 + c;
  const float v0 = s[0], v1 = s[128], v2 = s[256];
  float* d = out + (size_t)n*512 + 128 + c*3;
  d[0] = v0; d[1] = v1; d[2] = v2;
}

// ------------- TP + residual + norms: builds A2 [NP,512], TPV [NP,3,256] ---
// residual read from A2's old contents (= A0 s-half) and XVp bf16 planes
__global__ __launch_bounds__(256)
void k_tp(const u16* __restrict__ OL, const u16* __restrict__ ORr,
          const u16* __restrict__ XVpp,
          const float* __restrict__ w_ss, const float* __restrict__ w_sv,
          const float* __restrict__ w_vs, const float* __restrict__ w_vv,
          u16* A2, u16* __restrict__ TPV){
  const int n = (blockIdx.x << 1) + (threadIdx.x >> 7);
  const int h = threadIdx.x & 127;
  const u16* ol  = OL  + (size_t)n * 512;
  const u16* orv = ORr + (size_t)n * 512;
  const float ls = bf2f(ol[h]),  rs = bf2f(orv[h]);
  const float lv0=bf2f(ol[128+h]),  lv1=bf2f(ol[256+h]),  lv2=bf2f(ol[384+h]);
  const float rv0=bf2f(orv[128+h]), rv1=bf2f(orv[256+h]), rv2=bf2f(orv[384+h]);
  const float wss=w_ss[h], wsv=w_sv[h], wvs=w_vs[h], wvv=w_vv[h];
  float sa = wss * ls * rs;
  float sb = wvv * (lv0*rv0 + lv1*rv1 + lv2*rv2) * 0.5773502691896258f;
  float va0 = wsv*ls*rv0, va1 = wsv*ls*rv1, va2 = wsv*ls*rv2;
  float vb0 = wvs*lv0*rs, vb1 = wvs*lv1*rs, vb2 = wvs*lv2*rs;
  if(n < NN){
    const u16* a0 = A2 + (size_t)n * 512;
    const u16* xv = XVpp + (size_t)n * 768;
    sa += bf2f(a0[h]); sb += bf2f(a0[128 + h]);
    va0 += bf2f(xv[h]);       va1 += bf2f(xv[256 + h]);  va2 += bf2f(xv[512 + h]);
    vb0 += bf2f(xv[128 + h]); vb1 += bf2f(xv[384 + h]);  vb2 += bf2f(xv[640 + h]);
  }
  u16* a2 = A2 + (size_t)n * 512;
  a2[h]       = f2bf(sa);
  a2[128 + h] = f2bf(sb);
  a2[256 + h] = f2bf(sqrtf(va0*va0 + va1*va1 + va2*va2));
  a2[384 + h] = f2bf(sqrtf(vb0*vb0 + vb1*vb1 + vb2*vb2));
  u16* tv = TPV + (size_t)n * 768;
  tv[h]       = f2bf(va0);  tv[128 + h] = f2bf(vb0);
  tv[256 + h] = f2bf(va1);  tv[384 + h] = f2bf(vb1);
  tv[512 + h] = f2bf(va2);  tv[640 + h] = f2bf(vb2);
}

extern "C" void kernel_launch(void* const* d_in, const int* in_sizes, int n_in,
                              void* d_out, int out_size, void* d_ws, size_t ws_size,
                              hipStream_t stream){
  const float* x      = (const float*)d_in[0];
  const float* fcl1_w = (const float*)d_in[1];  const float* fcl1_b = (const float*)d_in[2];
  const float* fcl2_w = (const float*)d_in[3];  const float* fcl2_b = (const float*)d_in[4];
  const float* fcr1_w = (const float*)d_in[5];  const float* fcr1_b = (const float*)d_in[6];
  const float* fcr2_w = (const float*)d_in[7];  const float* fcr2_b = (const float*)d_in[8];
  const float* fcp1_w = (const float*)d_in[9];  const float* fcp1_b = (const float*)d_in[10];
  const float* fcp2_w = (const float*)d_in[11]; const float* fcp2_b = (const float*)d_in[12];
  const float* Wl0 = (const float*)d_in[13]; const float* bl0 = (const float*)d_in[14];
  const float* Wl1 = (const float*)d_in[15];
  const float* Wr0 = (const float*)d_in[16]; const float* br0 = (const float*)d_in[17];
  const float* Wr1 = (const float*)d_in[18];
  const float* Wp0 = (const float*)d_in[19]; const float* bp0 = (const float*)d_in[20];
  const float* Wp1 = (const float*)d_in[21];
  const float* w_ss = (const float*)d_in[22]; const float* w_sv = (const float*)d_in[23];
  const float* w_vs = (const float*)d_in[24]; const float* w_vv = (const float*)d_in[25];
  float* out = (float*)d_out;

  // ---- ws layout ----
  u16* WT = (u16*)d_ws;
  u16* wt_fcl1 = WT + 0*262144;
  u16* wt_fcl2 = WT + 1*262144;
  u16* wt_fcr1 = WT + 2*262144;
  u16* wt_fcr2 = WT + 3*262144;
  u16* wt_fcp1 = WT + 4*262144;
  u16* wt_fcp2 = WT + 5*262144;
  u16* wt_sm  = WT + 6*262144;
  u16* wt_Wl0 = wt_sm + 0*32768;
  u16* wt_Wl1 = wt_sm + 1*32768;
  u16* wt_Wr0 = wt_sm + 2*32768;
  u16* wt_Wr1 = wt_sm + 3*32768;
  u16* wt_Wp0 = wt_sm + 4*32768;
  u16* wt_Wp1 = wt_sm + 5*32768;
  char* base = (char*)d_ws;
  const size_t SZ512  = (size_t)NP * 512 * 2;
  const size_t SZ1024 = (size_t)NP * 1024 * 2;
  const size_t W_RES  = (size_t)4 << 20;
  u16* A0 = (u16*)(base + W_RES);                       // A0, later A2
  u16* Hl = (u16*)(base + W_RES + 1*SZ512);             // H_l, OL, H_p
  u16* Hr = (u16*)(base + W_RES + 2*SZ512);             // H_r, OR
  u16* BL = (u16*)(base + W_RES + 3*SZ512);             // ls/lv left; later TPV; later PVp
  u16* BR = (u16*)(base + W_RES + 3*SZ512 + SZ1024);    // ls/lv right; later PS/PV
  u16* XVp = (u16*)d_out;          // scratch: x vec bf16 planes [NP,3,256]
  float* PVp = (float*)BL;         // fp32 vec planes [NP,3,128]
  (void)ws_size; (void)in_sizes; (void)n_in; (void)out_size;

  // 1. weights -> bf16 transposed (tiled)
  k_wt<<<dim3(64,12), 256, 0, stream>>>(fcl1_w, fcl2_w, fcr1_w, fcr2_w, fcp1_w, fcp2_w,
                                        Wl0, Wl1, Wr0, Wr1, Wp0, Wp1, WT);
  // 2. A0 = [s | ||v||] bf16; XVp planes
  k_prep<<<NP, 256, 0, stream>>>(x, A0, XVp);
  // 3. fc1 (L,R)
  k_fc<0,2><<<RT*8, 256, 0, stream>>>(A0, A0, wt_fcl1, wt_fcr1,
                                      fcl1_b, fcr1_b, Hl, Hr, nullptr);
  // 4. fc2 (L,R) + gate vs XVp
  k_fc<1,2><<<RT*8, 256, 0, stream>>>(Hl, Hr, wt_fcl2, wt_fcr2,
                                      fcl2_b, fcr2_b, BL, BR, XVp);
  // 5. o3 linears (2 branches x 4 comps) -> OL(Hl), OR(Hr)
  k_o3<0><<<RT*8, 256, 0, stream>>>(BL, BR, wt_Wl0, wt_Wl1, wt_Wr0, wt_Wr1,
                                    bl0, br0, Hl, Hr, nullptr, nullptr);
  // 6. tensor product + residual + norms -> A2(A0), TPV(BL); residual from
  //    A0 s-half + XVp (bf16)
  k_tp<<<NP/2, 256, 0, stream>>>(Hl, Hr, XVp, w_ss, w_sv, w_vs, w_vv, A0, BL);
  // 7. fcp1
  k_fc<0,1><<<RT*4, 256, 0, stream>>>(A0, A0, wt_fcp1, wt_fcp1,
                                      fcp1_b, fcp1_b, Hl, Hl, nullptr);
  // 8. fcp2 + gate vs TPV(BL)
  k_fc<2,1><<<RT*4, 256, 0, stream>>>(Hl, Hl, wt_fcp2, wt_fcp2,
                                      fcp2_b, fcp2_b, BR, BR, BL);
  // 9. final o3 -> scalars to out; vectors to PVp (aliases BL, free now)
  k_o3<1><<<RT*4, 256, 0, stream>>>(BR, BR, wt_Wp0, wt_Wp1, nullptr, nullptr,
                                    bp0, bp0, nullptr, nullptr, out, PVp);
  // 10. interleave vector planes into out
  k_out<<<NN/2, 256, 0, stream>>>(PVp, out);
}